// Round 1
// baseline (523.583 us; speedup 1.0000x reference)
//
#include <hip/hip_runtime.h>
#include <hip/hip_bf16.h>

typedef unsigned short u16;
typedef __attribute__((ext_vector_type(8))) short bf16x8;
typedef __attribute__((ext_vector_type(4))) float f32x4;
typedef __attribute__((ext_vector_type(4))) u16 u16x4;

__device__ inline u16 f2bf(float f) {
  unsigned int x = __float_as_uint(f);
  unsigned int r = x + 0x7fffu + ((x >> 16) & 1u);
  return (u16)(r >> 16);
}

__device__ inline void gload16(const u16* g, u16* l) {
  __builtin_amdgcn_global_load_lds(
      (const __attribute__((address_space(1))) void*)g,
      (__attribute__((address_space(3))) void*)l, 16, 0, 0);
}

// ---------------- fp32 -> bf16 conversion ----------------
__global__ __launch_bounds__(256) void cvt_kernel(const float* __restrict__ in,
                                                  u16* __restrict__ out, long n4) {
  long i = (long)blockIdx.x * 256 + threadIdx.x;
  long stride = (long)gridDim.x * 256;
  for (; i < n4; i += stride) {
    float4 f = ((const float4*)in)[i];
    u16x4 u;
    u[0] = f2bf(f.x); u[1] = f2bf(f.y); u[2] = f2bf(f.z); u[3] = f2bf(f.w);
    ((u16x4*)out)[i] = u;
  }
}

// ---------------- lengths from key-padding mask (dtype-sniffing) ----------------
__global__ __launch_bounds__(256) void lengths_kernel(const void* __restrict__ mask,
                                                      int* __restrict__ lengths,
                                                      int TQ_, int TK_) {
  int b = blockIdx.x;
  unsigned int first = *(const unsigned int*)mask;  // mask[0,0,0] is true (len>=1024)
  int mode;             // 0: int32 0/1, 1: byte, 2: float32
  if (first == 1u) mode = 0;
  else if (first == 0x01010101u) mode = 1;
  else if (first == 0x3f800000u) mode = 2;
  else mode = 1;
  long base = (long)b * TQ_ * TK_;  // row q=0 of batch b
  int cnt = 0;
  for (int k = threadIdx.x; k < TK_; k += blockDim.x) {
    bool nz;
    if (mode == 0)      nz = ((const int*)mask)[base + k] != 0;
    else if (mode == 2) nz = ((const float*)mask)[base + k] != 0.f;
    else                nz = ((const unsigned char*)mask)[base + k] != 0;
    cnt += nz ? 1 : 0;
  }
#pragma unroll
  for (int o = 32; o > 0; o >>= 1) cnt += __shfl_xor(cnt, o);
  __shared__ int red[4];
  int wv = threadIdx.x >> 6, lane = threadIdx.x & 63;
  if (lane == 0) red[wv] = cnt;
  __syncthreads();
  if (threadIdx.x == 0) lengths[b] = red[0] + red[1] + red[2] + red[3];
}

// ---------------- B^T GEMM, 128x128 tile, 4 waves, 16x16x32 bf16 MFMA ----------------
// MODE 0: bf16 out row-major [M][N], +bias[col]
// MODE 1: bf16 out transposed  out[col*M + row], +bias[col]   (V^T)
// MODE 2: f32 out row-major, *scale, col>=len -> -inf          (scores)
// MODE 3: f32 out row-major plain                              (context)
template <int MODE>
__global__ __launch_bounds__(256) void gemm_bt(
    const u16* __restrict__ A, long sA,
    const u16* __restrict__ Bm, long sB,
    void* __restrict__ Out, long sO,
    const float* __restrict__ bias,
    const float* __restrict__ scale_ptr,
    const int* __restrict__ lengths,
    int M, int N, int K) {
  __shared__ u16 lA[128 * 32];
  __shared__ u16 lB[128 * 32];
  int tid = threadIdx.x;
  int w = tid >> 6, lane = tid & 63;
  int bx = blockIdx.x, by = blockIdx.y, z = blockIdx.z;
  const u16* A_ = A + (size_t)z * sA + (size_t)by * 128 * K;
  const u16* B_ = Bm + (size_t)z * sB + (size_t)bx * 128 * K;
  int wm = (w >> 1) * 64, wn = (w & 1) * 64;
  int lm = lane >> 4, ln = lane & 15;

  f32x4 acc[4][4] = {};

  // staging: 8 KB per operand per K-step; 8 chunks of 1KB (64 lanes x 16B)
  int c0 = w * 2, c1 = w * 2 + 1;
  int off0 = c0 * 1024 + lane * 16;  // byte offset in tile
  int off1 = c1 * 1024 + lane * 16;
  const u16* ga0 = A_ + (size_t)(off0 >> 6) * K + ((off0 & 63) >> 1);
  const u16* ga1 = A_ + (size_t)(off1 >> 6) * K + ((off1 & 63) >> 1);
  const u16* gb0 = B_ + (size_t)(off0 >> 6) * K + ((off0 & 63) >> 1);
  const u16* gb1 = B_ + (size_t)(off1 >> 6) * K + ((off1 & 63) >> 1);

  int nk = K >> 5;
  for (int kb = 0; kb < nk; ++kb) {
    gload16(ga0, &lA[c0 * 512]);
    gload16(ga1, &lA[c1 * 512]);
    gload16(gb0, &lB[c0 * 512]);
    gload16(gb1, &lB[c1 * 512]);
    ga0 += 32; ga1 += 32; gb0 += 32; gb1 += 32;
    __syncthreads();  // drains vmcnt: tile resident
    bf16x8 af[4], bfr[4];
#pragma unroll
    for (int mi = 0; mi < 4; ++mi)
      af[mi] = *(const bf16x8*)&lA[(wm + mi * 16 + ln) * 32 + lm * 8];
#pragma unroll
    for (int ni = 0; ni < 4; ++ni)
      bfr[ni] = *(const bf16x8*)&lB[(wn + ni * 16 + ln) * 32 + lm * 8];
#pragma unroll
    for (int mi = 0; mi < 4; ++mi)
#pragma unroll
      for (int ni = 0; ni < 4; ++ni)
        acc[mi][ni] = __builtin_amdgcn_mfma_f32_16x16x32_bf16(af[mi], bfr[ni],
                                                              acc[mi][ni], 0, 0, 0);
    __syncthreads();
  }

  float scl = 0.f;
  int len = 0;
  if (MODE == 2) { scl = *scale_ptr; len = lengths[z]; }

#pragma unroll
  for (int mi = 0; mi < 4; ++mi) {
#pragma unroll
    for (int ni = 0; ni < 4; ++ni) {
      int r0 = by * 128 + wm + mi * 16 + lm * 4;
      int c = bx * 128 + wn + ni * 16 + ln;
      f32x4 v = acc[mi][ni];
      if (MODE == 0) {
        float bval = bias[c];
        u16* o = (u16*)Out + (size_t)z * sO;
#pragma unroll
        for (int r = 0; r < 4; ++r) o[(size_t)(r0 + r) * N + c] = f2bf(v[r] + bval);
      } else if (MODE == 1) {
        float bval = bias[c];
        u16* o = (u16*)Out + (size_t)z * sO;
        u16x4 pk;
#pragma unroll
        for (int r = 0; r < 4; ++r) pk[r] = f2bf(v[r] + bval);
        *(u16x4*)&o[(size_t)c * M + r0] = pk;
      } else if (MODE == 2) {
        float* o = (float*)Out + (size_t)z * sO;
#pragma unroll
        for (int r = 0; r < 4; ++r) {
          float val = v[r] * scl;
          if (c >= len) val = -INFINITY;
          o[(size_t)(r0 + r) * N + c] = val;
        }
      } else {
        float* o = (float*)Out + (size_t)z * sO;
#pragma unroll
        for (int r = 0; r < 4; ++r) o[(size_t)(r0 + r) * N + c] = v[r];
      }
    }
  }
}

// ---------------- row softmax over TK=2048, in-place fp32 + bf16 copy ----------------
__global__ __launch_bounds__(256) void softmax_kernel(float* __restrict__ W,
                                                      u16* __restrict__ P, int TK_) {
  size_t row = blockIdx.x;
  float* wr = W + row * (size_t)TK_;
  u16* pr = P + row * (size_t)TK_;
  int t = threadIdx.x;
  int wv = t >> 6, lane = t & 63;
  float4 a = *(const float4*)&wr[t * 4];
  float4 c = *(const float4*)&wr[1024 + t * 4];
  float m = fmaxf(fmaxf(fmaxf(a.x, a.y), fmaxf(a.z, a.w)),
                  fmaxf(fmaxf(c.x, c.y), fmaxf(c.z, c.w)));
#pragma unroll
  for (int o = 32; o > 0; o >>= 1) m = fmaxf(m, __shfl_xor(m, o));
  __shared__ float red[4];
  if (lane == 0) red[wv] = m;
  __syncthreads();
  m = fmaxf(fmaxf(red[0], red[1]), fmaxf(red[2], red[3]));
  float e0 = __expf(a.x - m), e1 = __expf(a.y - m), e2 = __expf(a.z - m), e3 = __expf(a.w - m);
  float e4 = __expf(c.x - m), e5 = __expf(c.y - m), e6 = __expf(c.z - m), e7 = __expf(c.w - m);
  float s = e0 + e1 + e2 + e3 + e4 + e5 + e6 + e7;
#pragma unroll
  for (int o = 32; o > 0; o >>= 1) s += __shfl_xor(s, o);
  __syncthreads();  // red reuse
  if (lane == 0) red[wv] = s;
  __syncthreads();
  s = red[0] + red[1] + red[2] + red[3];
  float inv = 1.0f / s;
  float4 oa = make_float4(e0 * inv, e1 * inv, e2 * inv, e3 * inv);
  float4 ob = make_float4(e4 * inv, e5 * inv, e6 * inv, e7 * inv);
  *(float4*)&wr[t * 4] = oa;
  *(float4*)&wr[1024 + t * 4] = ob;
  u16x4 pa, pb;
  pa[0] = f2bf(oa.x); pa[1] = f2bf(oa.y); pa[2] = f2bf(oa.z); pa[3] = f2bf(oa.w);
  pb[0] = f2bf(ob.x); pb[1] = f2bf(ob.y); pb[2] = f2bf(ob.z); pb[3] = f2bf(ob.w);
  *(u16x4*)&pr[t * 4] = pa;
  *(u16x4*)&pr[1024 + t * 4] = pb;
}

extern "C" void kernel_launch(void* const* d_in, const int* in_sizes, int n_in,
                              void* d_out, int out_size, void* d_ws, size_t ws_size,
                              hipStream_t stream) {
  const int B_ = 8, TQ_ = 1024, TK_ = 2048, F_ = 1024;
  const float* inputs = (const float*)d_in[0];
  const float* features = (const float*)d_in[1];
  const void* mask = d_in[2];
  const float* Wq = (const float*)d_in[3];
  const float* bq = (const float*)d_in[4];
  const float* Wk = (const float*)d_in[5];
  const float* bk = (const float*)d_in[6];
  const float* Wv = (const float*)d_in[7];
  const float* bv = (const float*)d_in[8];
  const float* scale = (const float*)d_in[9];

  char* ws = (char*)d_ws;
  size_t o = 0;
  auto alloc = [&](size_t bytes) {
    size_t r = o;
    o += (bytes + 255) & ~(size_t)255;
    return r;
  };
  u16* inB = (u16*)(ws + alloc((size_t)B_ * TQ_ * F_ * 2));
  u16* ftB = (u16*)(ws + alloc((size_t)B_ * TK_ * F_ * 2));
  u16* wqB = (u16*)(ws + alloc((size_t)F_ * F_ * 2));
  u16* wkB = (u16*)(ws + alloc((size_t)F_ * F_ * 2));
  u16* wvB = (u16*)(ws + alloc((size_t)F_ * F_ * 2));
  u16* Qb = (u16*)(ws + alloc((size_t)B_ * TQ_ * F_ * 2));
  u16* Kb = (u16*)(ws + alloc((size_t)B_ * TK_ * F_ * 2));
  u16* Vt = (u16*)(ws + alloc((size_t)B_ * F_ * TK_ * 2));
  u16* P = (u16*)(ws + alloc((size_t)B_ * TQ_ * TK_ * 2));
  int* lens = (int*)(ws + alloc(B_ * sizeof(int)));

  float* outCtx = (float*)d_out;                        // [B,TQ,F]
  float* outW = (float*)d_out + (size_t)B_ * TQ_ * F_;  // [B,TQ,TK]

  auto cvt = [&](const float* in, u16* out, long n) {
    long n4 = n / 4;
    long g = (n4 + 255) / 256;
    int grid = (int)(g < 2048 ? g : 2048);
    cvt_kernel<<<dim3(grid), dim3(256), 0, stream>>>(in, out, n4);
  };
  cvt(inputs, inB, (long)B_ * TQ_ * F_);
  cvt(features, ftB, (long)B_ * TK_ * F_);
  cvt(Wq, wqB, (long)F_ * F_);
  cvt(Wk, wkB, (long)F_ * F_);
  cvt(Wv, wvB, (long)F_ * F_);

  lengths_kernel<<<dim3(B_), dim3(256), 0, stream>>>(mask, lens, TQ_, TK_);

  // Q = inputs @ Wq^T + bq  -> bf16 [8192,1024]
  gemm_bt<0><<<dim3(F_ / 128, (B_ * TQ_) / 128, 1), dim3(256), 0, stream>>>(
      inB, 0, wqB, 0, Qb, 0, bq, nullptr, nullptr, B_ * TQ_, F_, F_);
  // K = features @ Wk^T + bk -> bf16 [16384,1024]
  gemm_bt<0><<<dim3(F_ / 128, (B_ * TK_) / 128, 1), dim3(256), 0, stream>>>(
      ftB, 0, wkB, 0, Kb, 0, bk, nullptr, nullptr, B_ * TK_, F_, F_);
  // V^T[b,d,k] = (features @ Wv^T + bv)^T -> bf16 [B][1024][2048]
  gemm_bt<1><<<dim3(F_ / 128, TK_ / 128, B_), dim3(256), 0, stream>>>(
      ftB, (long)TK_ * F_, wvB, 0, Vt, (long)F_ * TK_, bv, nullptr, nullptr,
      TK_, F_, F_);
  // scores[b,q,k] = scale * Q K^T, masked -> f32 into weights region of d_out
  gemm_bt<2><<<dim3(TK_ / 128, TQ_ / 128, B_), dim3(256), 0, stream>>>(
      Qb, (long)TQ_ * F_, Kb, (long)TK_ * F_, outW, (long)TQ_ * TK_, nullptr,
      scale, lens, TQ_, TK_, F_);
  // softmax rows, in-place + bf16 P
  softmax_kernel<<<dim3(B_ * TQ_), dim3(256), 0, stream>>>(outW, P, TK_);
  // context[b,q,d] = P @ V  (as B^T gemm vs V^T)
  gemm_bt<3><<<dim3(F_ / 128, TQ_ / 128, B_), dim3(256), 0, stream>>>(
      P, (long)TQ_ * TK_, Vt, (long)F_ * TK_, outCtx, (long)TQ_ * F_, nullptr,
      nullptr, nullptr, TQ_, F_, TK_);
}

// Round 2
// 441.521 us; speedup vs baseline: 1.1859x; 1.1859x over previous
//
#include <hip/hip_runtime.h>
#include <hip/hip_bf16.h>

typedef unsigned short u16;
typedef __attribute__((ext_vector_type(8))) short bf16x8;
typedef __attribute__((ext_vector_type(4))) float f32x4;
typedef __attribute__((ext_vector_type(4))) u16 u16x4;

__device__ inline u16 f2bf(float f) {
  unsigned int x = __float_as_uint(f);
  unsigned int r = x + 0x7fffu + ((x >> 16) & 1u);
  return (u16)(r >> 16);
}

__device__ inline void gload16(const u16* g, u16* l) {
  __builtin_amdgcn_global_load_lds(
      (const __attribute__((address_space(1))) void*)g,
      (__attribute__((address_space(3))) void*)l, 16, 0, 0);
}

#define BAR() asm volatile("s_barrier" ::: "memory")
#define VMCNT4() asm volatile("s_waitcnt vmcnt(4)" ::: "memory")
#define VMCNT0() asm volatile("s_waitcnt vmcnt(0)" ::: "memory")

// ---------------- fp32 -> bf16 conversion ----------------
__global__ __launch_bounds__(256) void cvt_kernel(const float* __restrict__ in,
                                                  u16* __restrict__ out, long n4) {
  long i = (long)blockIdx.x * 256 + threadIdx.x;
  long stride = (long)gridDim.x * 256;
  for (; i < n4; i += stride) {
    float4 f = ((const float4*)in)[i];
    u16x4 u;
    u[0] = f2bf(f.x); u[1] = f2bf(f.y); u[2] = f2bf(f.z); u[3] = f2bf(f.w);
    ((u16x4*)out)[i] = u;
  }
}

// ---------------- lengths from key-padding mask (dtype-sniffing) ----------------
__global__ __launch_bounds__(256) void lengths_kernel(const void* __restrict__ mask,
                                                      int* __restrict__ lengths,
                                                      int TQ_, int TK_) {
  int b = blockIdx.x;
  unsigned int first = *(const unsigned int*)mask;  // mask[0,0,0] is true (len>=1024)
  int mode;  // 0: int32 0/1, 1: byte, 2: float32
  if (first == 1u) mode = 0;
  else if (first == 0x01010101u) mode = 1;
  else if (first == 0x3f800000u) mode = 2;
  else mode = 1;
  long base = (long)b * TQ_ * TK_;
  int cnt = 0;
  for (int k = threadIdx.x; k < TK_; k += blockDim.x) {
    bool nz;
    if (mode == 0)      nz = ((const int*)mask)[base + k] != 0;
    else if (mode == 2) nz = ((const float*)mask)[base + k] != 0.f;
    else                nz = ((const unsigned char*)mask)[base + k] != 0;
    cnt += nz ? 1 : 0;
  }
#pragma unroll
  for (int o = 32; o > 0; o >>= 1) cnt += __shfl_xor(cnt, o);
  __shared__ int red[4];
  int wv = threadIdx.x >> 6, lane = threadIdx.x & 63;
  if (lane == 0) red[wv] = cnt;
  __syncthreads();
  if (threadIdx.x == 0) lengths[b] = red[0] + red[1] + red[2] + red[3];
}

// ======== 256x256 8-phase B^T GEMM (T1 xcd-swz, T2 lds-swz, T3/T4 counted vmcnt, T5 setprio)
// MODE 0: bf16 out row-major [M][N], +bias[col]
// MODE 1: bf16 out transposed  out[col*M + row], +bias[col]   (V^T)
// MODE 2: f32 out row-major, *scale, col>=len -> -inf          (scores)
// MODE 3: f32 out row-major plain                              (context)
#define DO_MFMA(pp)                                                                             \
  __builtin_amdgcn_s_setprio(1);                                                                \
  acc[(pp)*2+0][0] = __builtin_amdgcn_mfma_f32_16x16x32_bf16(af[0][0], bfr[0][0], acc[(pp)*2+0][0], 0, 0, 0); \
  acc[(pp)*2+0][1] = __builtin_amdgcn_mfma_f32_16x16x32_bf16(af[0][0], bfr[1][0], acc[(pp)*2+0][1], 0, 0, 0); \
  acc[(pp)*2+0][2] = __builtin_amdgcn_mfma_f32_16x16x32_bf16(af[0][0], bfr[2][0], acc[(pp)*2+0][2], 0, 0, 0); \
  acc[(pp)*2+0][3] = __builtin_amdgcn_mfma_f32_16x16x32_bf16(af[0][0], bfr[3][0], acc[(pp)*2+0][3], 0, 0, 0); \
  acc[(pp)*2+1][0] = __builtin_amdgcn_mfma_f32_16x16x32_bf16(af[1][0], bfr[0][0], acc[(pp)*2+1][0], 0, 0, 0); \
  acc[(pp)*2+1][1] = __builtin_amdgcn_mfma_f32_16x16x32_bf16(af[1][0], bfr[1][0], acc[(pp)*2+1][1], 0, 0, 0); \
  acc[(pp)*2+1][2] = __builtin_amdgcn_mfma_f32_16x16x32_bf16(af[1][0], bfr[2][0], acc[(pp)*2+1][2], 0, 0, 0); \
  acc[(pp)*2+1][3] = __builtin_amdgcn_mfma_f32_16x16x32_bf16(af[1][0], bfr[3][0], acc[(pp)*2+1][3], 0, 0, 0); \
  acc[(pp)*2+0][0] = __builtin_amdgcn_mfma_f32_16x16x32_bf16(af[0][1], bfr[0][1], acc[(pp)*2+0][0], 0, 0, 0); \
  acc[(pp)*2+0][1] = __builtin_amdgcn_mfma_f32_16x16x32_bf16(af[0][1], bfr[1][1], acc[(pp)*2+0][1], 0, 0, 0); \
  acc[(pp)*2+0][2] = __builtin_amdgcn_mfma_f32_16x16x32_bf16(af[0][1], bfr[2][1], acc[(pp)*2+0][2], 0, 0, 0); \
  acc[(pp)*2+0][3] = __builtin_amdgcn_mfma_f32_16x16x32_bf16(af[0][1], bfr[3][1], acc[(pp)*2+0][3], 0, 0, 0); \
  acc[(pp)*2+1][0] = __builtin_amdgcn_mfma_f32_16x16x32_bf16(af[1][1], bfr[0][1], acc[(pp)*2+1][0], 0, 0, 0); \
  acc[(pp)*2+1][1] = __builtin_amdgcn_mfma_f32_16x16x32_bf16(af[1][1], bfr[1][1], acc[(pp)*2+1][1], 0, 0, 0); \
  acc[(pp)*2+1][2] = __builtin_amdgcn_mfma_f32_16x16x32_bf16(af[1][1], bfr[2][1], acc[(pp)*2+1][2], 0, 0, 0); \
  acc[(pp)*2+1][3] = __builtin_amdgcn_mfma_f32_16x16x32_bf16(af[1][1], bfr[3][1], acc[(pp)*2+1][3], 0, 0, 0); \
  __builtin_amdgcn_s_setprio(0);

template <int MODE>
__global__ __launch_bounds__(512, 2) void gemm8p(
    const u16* __restrict__ A, long sA,
    const u16* __restrict__ Bm, long sB,
    void* __restrict__ Out, long sO,
    const float* __restrict__ bias,
    const float* __restrict__ scale_ptr,
    const int* __restrict__ lengths,
    int M, int N, int K) {
  extern __shared__ __align__(16) u16 lds[];  // 2 slots x (A 32KB + B 32KB) = 128KB
  const int tid = threadIdx.x;
  const int w = tid >> 6, lane = tid & 63;
  const int lm = lane >> 4, ln = lane & 15;
  const int wm = w >> 2, wn = w & 3;  // 2(M) x 4(N) waves

  // T1: bijective XCD swizzle on linearized block id (all grids are %8==0)
  int gx = gridDim.x, gy = gridDim.y;
  int nwg = gx * gy * gridDim.z;
  int id = blockIdx.x + gx * (blockIdx.y + gy * blockIdx.z);
  int cpx = nwg >> 3;
  int swz = (id & 7) * cpx + (id >> 3);
  int bx = swz % gx;
  int tmp = swz / gx;
  int by = tmp % gy;
  int z = tmp / gy;

  const u16* A_ = A + (size_t)z * sA + (size_t)by * 256 * K;
  const u16* B_ = Bm + (size_t)z * sB + (size_t)bx * 256 * K;

  // per-thread staging source offsets (elements), T2 inverse-swizzled (tile 0)
  int srcOff[2][2];
#pragma unroll
  for (int half = 0; half < 2; ++half)
#pragma unroll
    for (int l = 0; l < 2; ++l) {
      int off = half * 16384 + l * 8192 + tid * 16;  // LDS byte offset within operand tile
      int row = off >> 7;
      int sb = (off & 127) ^ ((row & 7) << 4);
      srcOff[half][l] = row * K + (sb >> 1);
    }

  // ds_read element addressing (swizzled)
  const int aBase = (wm * 128 + ln) * 64;
  const int bBase = (wn * 64 + ln) * 64;
  const int swzk0 = ((0 + lm) ^ (ln & 7)) * 8;
  const int swzk1 = ((4 + lm) ^ (ln & 7)) * 8;

  f32x4 acc[8][4] = {};
  bf16x8 af[2][2];
  bf16x8 bfr[4][2];

  auto stage = [&](const u16* gb, int slot, int isB, int half, int t) {
#pragma unroll
    for (int l = 0; l < 2; ++l)
      gload16(gb + srcOff[half][l] + t * 64,
              (u16*)((char*)&lds[0] + slot * 65536 + isB * 32768 + half * 16384 +
                     l * 8192 + w * 1024));
  };
  auto ldA = [&](int slot, int pp) {
#pragma unroll
    for (int m2 = 0; m2 < 2; ++m2) {
      af[m2][0] = *(const bf16x8*)&lds[slot * 32768 + aBase + (pp * 2 + m2) * 1024 + swzk0];
      af[m2][1] = *(const bf16x8*)&lds[slot * 32768 + aBase + (pp * 2 + m2) * 1024 + swzk1];
    }
  };
  auto ldB = [&](int slot) {
#pragma unroll
    for (int ni = 0; ni < 4; ++ni) {
      bfr[ni][0] = *(const bf16x8*)&lds[slot * 32768 + 16384 + bBase + ni * 1024 + swzk0];
      bfr[ni][1] = *(const bf16x8*)&lds[slot * 32768 + 16384 + bBase + ni * 1024 + swzk1];
    }
  };

  // prologue: tile0 (B0,B1,A0,A1)->slot0 ; tile1 (B0,B1)->slot1 ; wait tile0
  stage(B_, 0, 1, 0, 0);
  stage(B_, 0, 1, 1, 0);
  stage(A_, 0, 0, 0, 0);
  stage(A_, 0, 0, 1, 0);
  stage(B_, 1, 1, 0, 1);
  stage(B_, 1, 1, 1, 1);
  VMCNT4();
  BAR();

  const int nt = K >> 6;
  const int nIt = nt >> 1;
  for (int it = 0; it < nIt; ++it) {
    const int t = 2 * it;
    const bool last = (it == nIt - 1);
    // P1: compute tile t (slot0) mrep 0-1; stage A0(t+1)->slot1
    ldB(0); ldA(0, 0);
    stage(A_, 1, 0, 0, t + 1);
    BAR(); DO_MFMA(0); BAR();
    // P2: mrep 2-3; stage A1(t+1)->slot1 ; B0(t+2)->slot0
    ldA(0, 1);
    stage(A_, 1, 0, 1, t + 1);
    if (!last) stage(B_, 0, 1, 0, t + 2);
    BAR(); DO_MFMA(1); BAR();
    // P3: mrep 4-5; stage B1(t+2)->slot0
    ldA(0, 2);
    if (!last) stage(B_, 0, 1, 1, t + 2);
    BAR(); DO_MFMA(2); BAR();
    // P4: mrep 6-7; vmcnt guards tile t+1 arrival
    ldA(0, 3);
    BAR(); DO_MFMA(3);
    if (!last) { VMCNT4(); } else { VMCNT0(); }
    BAR();
    // P5: compute tile t+1 (slot1) mrep 0-1; stage A0(t+2)->slot0
    ldB(1); ldA(1, 0);
    if (!last) stage(A_, 0, 0, 0, t + 2);
    BAR(); DO_MFMA(0); BAR();
    // P6: mrep 2-3; stage A1(t+2)->slot0
    ldA(1, 1);
    if (!last) stage(A_, 0, 0, 1, t + 2);
    BAR(); DO_MFMA(1); BAR();
    // P7: mrep 4-5; stage B0(t+3)->slot1
    ldA(1, 2);
    if (!last) stage(B_, 1, 1, 0, t + 3);
    BAR(); DO_MFMA(2); BAR();
    // P8: mrep 6-7; stage B1(t+3)->slot1; vmcnt guards tile t+2 arrival
    ldA(1, 3);
    if (!last) stage(B_, 1, 1, 1, t + 3);
    BAR(); DO_MFMA(3);
    if (!last) { VMCNT4(); }
    BAR();
  }

  // -------- epilogue --------
  float scl = 0.f;
  int len = 0;
  if (MODE == 2) { scl = *scale_ptr; len = lengths[z]; }
  const int rowBase = by * 256 + wm * 128 + lm * 4;
  const int colBase = bx * 256 + wn * 64 + ln;
#pragma unroll
  for (int mi = 0; mi < 8; ++mi) {
#pragma unroll
    for (int ni = 0; ni < 4; ++ni) {
      int r0 = rowBase + mi * 16;
      int c = colBase + ni * 16;
      f32x4 v = acc[mi][ni];
      if (MODE == 0) {
        float bval = bias[c];
        u16* o = (u16*)Out + (size_t)z * sO;
#pragma unroll
        for (int r = 0; r < 4; ++r) o[(size_t)(r0 + r) * N + c] = f2bf(v[r] + bval);
      } else if (MODE == 1) {
        float bval = bias[c];
        u16* o = (u16*)Out + (size_t)z * sO;
        u16x4 pk;
#pragma unroll
        for (int r = 0; r < 4; ++r) pk[r] = f2bf(v[r] + bval);
        *(u16x4*)&o[(size_t)c * M + r0] = pk;
      } else if (MODE == 2) {
        float* o = (float*)Out + (size_t)z * sO;
#pragma unroll
        for (int r = 0; r < 4; ++r) {
          float val = v[r] * scl;
          if (c >= len) val = -INFINITY;
          o[(size_t)(r0 + r) * N + c] = val;
        }
      } else {
        float* o = (float*)Out + (size_t)z * sO;
#pragma unroll
        for (int r = 0; r < 4; ++r) o[(size_t)(r0 + r) * N + c] = v[r];
      }
    }
  }
}

// ---------------- row softmax over TK=2048, in-place fp32 + bf16 copy ----------------
__global__ __launch_bounds__(256) void softmax_kernel(float* __restrict__ W,
                                                      u16* __restrict__ P, int TK_) {
  size_t row = blockIdx.x;
  float* wr = W + row * (size_t)TK_;
  u16* pr = P + row * (size_t)TK_;
  int t = threadIdx.x;
  int wv = t >> 6, lane = t & 63;
  float4 a = *(const float4*)&wr[t * 4];
  float4 c = *(const float4*)&wr[1024 + t * 4];
  float m = fmaxf(fmaxf(fmaxf(a.x, a.y), fmaxf(a.z, a.w)),
                  fmaxf(fmaxf(c.x, c.y), fmaxf(c.z, c.w)));
#pragma unroll
  for (int o = 32; o > 0; o >>= 1) m = fmaxf(m, __shfl_xor(m, o));
  __shared__ float red[4];
  if (lane == 0) red[wv] = m;
  __syncthreads();
  m = fmaxf(fmaxf(red[0], red[1]), fmaxf(red[2], red[3]));
  float e0 = __expf(a.x - m), e1 = __expf(a.y - m), e2 = __expf(a.z - m), e3 = __expf(a.w - m);
  float e4 = __expf(c.x - m), e5 = __expf(c.y - m), e6 = __expf(c.z - m), e7 = __expf(c.w - m);
  float s = e0 + e1 + e2 + e3 + e4 + e5 + e6 + e7;
#pragma unroll
  for (int o = 32; o > 0; o >>= 1) s += __shfl_xor(s, o);
  __syncthreads();
  if (lane == 0) red[wv] = s;
  __syncthreads();
  s = red[0] + red[1] + red[2] + red[3];
  float inv = 1.0f / s;
  float4 oa = make_float4(e0 * inv, e1 * inv, e2 * inv, e3 * inv);
  float4 ob = make_float4(e4 * inv, e5 * inv, e6 * inv, e7 * inv);
  *(float4*)&wr[t * 4] = oa;
  *(float4*)&wr[1024 + t * 4] = ob;
  u16x4 pa, pb;
  pa[0] = f2bf(oa.x); pa[1] = f2bf(oa.y); pa[2] = f2bf(oa.z); pa[3] = f2bf(oa.w);
  pb[0] = f2bf(ob.x); pb[1] = f2bf(ob.y); pb[2] = f2bf(ob.z); pb[3] = f2bf(ob.w);
  *(u16x4*)&pr[t * 4] = pa;
  *(u16x4*)&pr[1024 + t * 4] = pb;
}

extern "C" void kernel_launch(void* const* d_in, const int* in_sizes, int n_in,
                              void* d_out, int out_size, void* d_ws, size_t ws_size,
                              hipStream_t stream) {
  const int B_ = 8, TQ_ = 1024, TK_ = 2048, F_ = 1024;
  const float* inputs = (const float*)d_in[0];
  const float* features = (const float*)d_in[1];
  const void* mask = d_in[2];
  const float* Wq = (const float*)d_in[3];
  const float* bq = (const float*)d_in[4];
  const float* Wk = (const float*)d_in[5];
  const float* bk = (const float*)d_in[6];
  const float* Wv = (const float*)d_in[7];
  const float* bv = (const float*)d_in[8];
  const float* scale = (const float*)d_in[9];

  char* ws = (char*)d_ws;
  size_t o = 0;
  auto alloc = [&](size_t bytes) {
    size_t r = o;
    o += (bytes + 255) & ~(size_t)255;
    return r;
  };
  u16* inB = (u16*)(ws + alloc((size_t)B_ * TQ_ * F_ * 2));
  u16* ftB = (u16*)(ws + alloc((size_t)B_ * TK_ * F_ * 2));
  u16* wqB = (u16*)(ws + alloc((size_t)F_ * F_ * 2));
  u16* wkB = (u16*)(ws + alloc((size_t)F_ * F_ * 2));
  u16* wvB = (u16*)(ws + alloc((size_t)F_ * F_ * 2));
  u16* Qb = (u16*)(ws + alloc((size_t)B_ * TQ_ * F_ * 2));
  u16* Kb = (u16*)(ws + alloc((size_t)B_ * TK_ * F_ * 2));
  u16* Vt = (u16*)(ws + alloc((size_t)B_ * F_ * TK_ * 2));
  u16* P = (u16*)(ws + alloc((size_t)B_ * TQ_ * TK_ * 2));
  int* lens = (int*)(ws + alloc(B_ * sizeof(int)));

  float* outCtx = (float*)d_out;                        // [B,TQ,F]
  float* outW = (float*)d_out + (size_t)B_ * TQ_ * F_;  // [B,TQ,TK]

  auto cvt = [&](const float* in, u16* out, long n) {
    long n4 = n / 4;
    long g = (n4 + 255) / 256;
    int grid = (int)(g < 2048 ? g : 2048);
    cvt_kernel<<<dim3(grid), dim3(256), 0, stream>>>(in, out, n4);
  };
  cvt(inputs, inB, (long)B_ * TQ_ * F_);
  cvt(features, ftB, (long)B_ * TK_ * F_);
  cvt(Wq, wqB, (long)F_ * F_);
  cvt(Wk, wkB, (long)F_ * F_);
  cvt(Wv, wvB, (long)F_ * F_);

  lengths_kernel<<<dim3(B_), dim3(256), 0, stream>>>(mask, lens, TQ_, TK_);

  // allow 128KB dynamic LDS (idempotent, capture-safe host call)
  (void)hipFuncSetAttribute(reinterpret_cast<const void*>(&gemm8p<0>),
                            hipFuncAttributeMaxDynamicSharedMemorySize, 131072);
  (void)hipFuncSetAttribute(reinterpret_cast<const void*>(&gemm8p<1>),
                            hipFuncAttributeMaxDynamicSharedMemorySize, 131072);
  (void)hipFuncSetAttribute(reinterpret_cast<const void*>(&gemm8p<2>),
                            hipFuncAttributeMaxDynamicSharedMemorySize, 131072);
  (void)hipFuncSetAttribute(reinterpret_cast<const void*>(&gemm8p<3>),
                            hipFuncAttributeMaxDynamicSharedMemorySize, 131072);

  // Q = inputs @ Wq^T + bq  -> bf16 [8192,1024]
  gemm8p<0><<<dim3(F_ / 256, (B_ * TQ_) / 256, 1), dim3(512), 131072, stream>>>(
      inB, 0, wqB, 0, Qb, 0, bq, nullptr, nullptr, B_ * TQ_, F_, F_);
  // K = features @ Wk^T + bk -> bf16 [16384,1024]
  gemm8p<0><<<dim3(F_ / 256, (B_ * TK_) / 256, 1), dim3(512), 131072, stream>>>(
      ftB, 0, wkB, 0, Kb, 0, bk, nullptr, nullptr, B_ * TK_, F_, F_);
  // V^T[b,d,k] = (features @ Wv^T + bv)^T -> bf16 [B][1024][2048]
  gemm8p<1><<<dim3(F_ / 256, TK_ / 256, B_), dim3(512), 131072, stream>>>(
      ftB, (long)TK_ * F_, wvB, 0, Vt, (long)F_ * TK_, bv, nullptr, nullptr,
      TK_, F_, F_);
  // scores[b,q,k] = scale * Q K^T, masked -> f32 into weights region of d_out
  gemm8p<2><<<dim3(TK_ / 256, TQ_ / 256, B_), dim3(512), 131072, stream>>>(
      Qb, (long)TQ_ * F_, Kb, (long)TK_ * F_, outW, (long)TQ_ * TK_, nullptr,
      scale, lens, TQ_, TK_, F_);
  // softmax rows, in-place + bf16 P
  softmax_kernel<<<dim3(B_ * TQ_), dim3(256), 0, stream>>>(outW, P, TK_);
  // context[b,q,d] = P @ V  (as B^T gemm vs V^T)
  gemm8p<3><<<dim3(F_ / 256, TQ_ / 256, B_), dim3(512), 131072, stream>>>(
      P, (long)TQ_ * TK_, Vt, (long)F_ * TK_, outCtx, (long)TQ_ * F_, nullptr,
      nullptr, nullptr, TQ_, F_, TK_);
}